// Round 7
// baseline (296.059 us; speedup 1.0000x reference)
//
#include <hip/hip_runtime.h>
#include <hip/hip_bf16.h>

typedef _Float16 v8h __attribute__((ext_vector_type(8)));
typedef _Float16 v4h __attribute__((ext_vector_type(4)));
typedef _Float16 v2h __attribute__((ext_vector_type(2)));
typedef float    v4f __attribute__((ext_vector_type(4)));

#define NTOT  16384
#define NN    70
#define STEPS 5
#define NWAVES 4                     // graphs per workgroup (1 graph per wave)
#define TPB   (64*NWAVES)            // 256 threads
#define NBLK  (NTOT/NWAVES)          // 4096 workgroups
// r4 vs r6 null result (201.4 == 201.5 us at LDS caps 11 vs 14, occupancy
// pinned 22% both): chip is WG-DISPATCH-RATE bound (~80 WG/us chip-wide;
// Little's-law fit across r0..r6). Fix: 4 graphs per WG -> 4096 WGs.
#define CATN  32                     // cat node stride (halves); k10-15,27-31
                                     // hit ZERO rows of weight A-frags -> only
                                     // finiteness needed (zero-init provides)
#define CATH  (80*CATN + 8)          // 2568 halves (+8 guard for node=79 b128)
#define USTR  232                    // U col stride (halves): 116 dw == 20 mod 32
#define UH    (10*USTR)              // 2320 halves: only the 10 real cols.
// P2 B-frag reads for phantom cols c=10..15 overflow into the SAME graph's cat
// slice (max offset 3704 < 4888 slice halves): finite garbage, D rows 10..15
// discarded. Harness-validated r2/r3/r6.

// epilogue weights (fp32, global scalar loads)
#define PWO1 0                       // 10 rows x 12: [Wo1[s][0..9], ann_coef, bo1[s]]
#define PWO2 120
#define PBO2 130
#define NWP  132

// fp16 fragment images (built by prep):
//  [0..1023]     P1 B-frags Wstack, 2 tiles:  nt*512 + lane*8 + j
//  [1024..2047]  P3 A-frags Wr | Wz:          mt*512 + lane*8 + j
//  [2048..2559]  P3 A-frag  Wh:               lane*8 + j
//  [2560..20479] adjacency frags:             2560 + (mt*7+kt)*512 + lane*8 + j
//  NOTE: A-frag image of M == B-frag image of M^T for 16x16x32 (identical
//  (lane,j)->(row/col,k) map), so adjacency images serve as swapped-P2's B operand.
#define OFR  1024
#define OFZ  1536
#define OFH  2048
#define OFA  2560
#define NWF  20480
#define PREPB 40

__device__ __align__(16) float    g_w[NWP];
__device__ __align__(16) _Float16 g_wf[NWF];
__device__ int g_flag;

__device__ __forceinline__ float fast_sigmoid(float x) {
    return __builtin_amdgcn_rcpf(1.0f + __expf(-x));
}
__device__ __forceinline__ float fast_tanh(float x) {
    float ax = fabsf(x);
    float e  = __expf(-2.0f * ax);
    float t  = (1.0f - e) * __builtin_amdgcn_rcpf(1.0f + e);
    return copysignf(t, x);
}

struct __align__(16) Smem {
    _Float16 U[UH];      // 4640 B: U[col=s][k=e*72+node]
    _Float16 cat[CATH];  // 5136 B: cat[node][k]; k0..9=a_in, 16..25=prop, 26=1
};
// 9776 B per graph; WG = 4 graphs = 39104 B -> 4 WG/CU = 16 waves/CU
// (VGPR 120 <= 128 tier also allows 16). 16 concurrent graphs/CU vs r6's 7.

// ---- prep: probe dtype; build epilogue weights + all fp16 fragment images ----
__global__ void prep_kernel(const void* annv, const void* Av,
    const void* winv, const void* binv, const void* wrv, const void* brv,
    const void* wzv, const void* bzv, const void* whv, const void* bhv,
    const void* wo1v, const void* bo1v, const void* wo2v, const void* bo2v)
{
    __shared__ int sflag;
    if (threadIdx.x == 0) {
        const unsigned short* u = (const unsigned short*)annv;
        int good = 0;
        for (int k = 0; k < 128; ++k) {
            unsigned short bb = u[k];
            int ex = (bb >> 7) & 0xFF;
            if (bb == 0 || (ex >= 101 && ex <= 131)) ++good;
        }
        sflag = (good >= 112) ? 1 : 0;
        if (blockIdx.x == 0) g_flag = sflag;
    }
    __syncthreads();
    const int f = sflag;
    #define RD(p, i) (f ? (float)((const __hip_bfloat16*)(p))[i] : ((const float*)(p))[i])
    const int tid = threadIdx.x;
    if (blockIdx.x == 0) {
        for (int idx = tid; idx < 120; idx += blockDim.x) {
            const int s = idx / 12, cc = idx - s*12;
            g_w[PWO1 + idx] = (cc < 11) ? RD(wo1v, s*11 + cc) : RD(bo1v, s);
        }
        for (int idx = tid; idx < 10; idx += blockDim.x) g_w[PWO2 + idx] = RD(wo2v, idx);
        if (tid == 0) { g_w[PBO2] = RD(bo2v, 0); g_w[PBO2+1] = 0.f; }
    }
    for (int idx = blockIdx.x*blockDim.x + tid; idx < NWF; idx += gridDim.x*blockDim.x) {
        float val = 0.f;
        if (idx < OFR) {
            // P1 B-frag: B[k][col=(e,s)]; k 16..25 -> Win[e][s][k-16], k 26 -> b_in
            const int nt = idx >> 9, rem = idx & 511, lane = rem >> 3, j = rem & 7;
            const int k = ((lane >> 4) << 3) + j, col = nt*16 + (lane & 15);
            if (col < 30) {
                const int e = col / 10, s = col - e*10;
                if (k >= 16 && k < 26) val = RD(winv, e*100 + s*10 + (k-16));
                else if (k == 26)      val = RD(binv, e*10 + s);
            }
        } else if (idx < OFH) {
            // P3 A-frags Wr/Wz: A[row=s][k]; k<10 -> W[s][k], 16..25 -> W[s][10+..], 26 -> bias
            const int i2 = idx - OFR;
            const int mt = i2 >> 9, rem = i2 & 511, lane = rem >> 3, j = rem & 7;
            const int k = ((lane >> 4) << 3) + j, s = lane & 15;
            if (s < 10) {
                const void* Wv = mt ? wzv : wrv;
                const void* bv = mt ? bzv : brv;
                if (k < 10)                 val = RD(Wv, s*20 + k);
                else if (k >= 16 && k < 26) val = RD(Wv, s*20 + 10 + (k-16));
                else if (k == 26)           val = RD(bv, s);
            }
        } else if (idx < OFA) {
            const int i2 = idx - OFH;
            const int lane = i2 >> 3, j = i2 & 7;
            const int k = ((lane >> 4) << 3) + j, s = lane & 15;
            if (s < 10) {
                if (k < 10)                 val = RD(whv, s*20 + k);
                else if (k >= 16 && k < 26) val = RD(whv, s*20 + 10 + (k-16));
                else if (k == 26)           val = RD(bhv, s);
            }
        } else {
            // adjacency frag: A[m=node][k=e*72+mm]; zero at pads (incl. k>=216)
            const int i2 = idx - OFA;
            const int w = i2 / 3584, rem = i2 - w*3584;
            const int kt = rem >> 9, r2 = rem & 511, lane = r2 >> 3, j = r2 & 7;
            const int m = w*16 + (lane & 15);
            const int k = kt*32 + ((lane >> 4) << 3) + j;
            const int e = k / 72, mm = k - e*72;
            if (m < NN && e < 3 && mm < NN) val = RD(Av, m*210 + e*70 + mm);
        }
        g_wf[idx] = (_Float16)val;
    }
    #undef RD
}

template<typename T>
__device__ __forceinline__ void run_impl(const void* annv, void* outv, Smem& sm,
                                         const int lane, const int gid)
{
    const T* ann_g = (const T*)annv;
    T* out_g       = (T*)outv;
    const int q    = lane >> 4;
    const int c    = lane & 15;
    const float* __restrict__ gw = g_w;

    // ---- preload ALL fragments as loop-hoisted arrays (r4 schedule: compiler
    //      keeps what fits in ~120 VGPRs and batches reloads early; do NOT pin
    //      with sched_barrier or stanzas -- r2/r3 lesson, +15 us/block)
    const v8h w1f0 = *(const v8h*)&g_wf[       lane*8];
    const v8h w1f1 = *(const v8h*)&g_wf[512  + lane*8];
    const v8h wrf  = *(const v8h*)&g_wf[OFR  + lane*8];
    const v8h wzf  = *(const v8h*)&g_wf[OFZ  + lane*8];
    const v8h whf  = *(const v8h*)&g_wf[OFH  + lane*8];
    v8h adj[35];
    #pragma unroll
    for (int i = 0; i < 35; ++i)
        adj[i] = *(const v8h*)&g_wf[OFA + i*512 + lane*8];

    // ---- zero own LDS slice (phantom rows/cols + slack k-slots MUST be finite)
    {
        const int4 zz = {0,0,0,0};
        int4* z = (int4*)&sm;
        #pragma unroll 4
        for (int i = lane; i < (int)(sizeof(Smem)/16); i += 64) z[i] = zz;
    }
    __syncthreads();

    // ---- seed: prop[0]=ann at k=16, bias-one at k=26
    for (int n2 = lane; n2 < NN; n2 += 64) {
        sm.cat[n2*CATN + 16] = (_Float16)(float)ann_g[gid*NN + n2];
        sm.cat[n2*CATN + 26] = (_Float16)1.0f;
    }
    __syncthreads();

    // ---- P1: ins(prop) -> U   (A=cat rows, B=Wstack frags)
    #define PHASE1() do {                                                        \
        _Pragma("unroll")                                                        \
        for (int mt = 0; mt < 5; ++mt) {                                         \
            const v8h af = *(const v8h*)&sm.cat[(mt*16 + c)*CATN + q*8];         \
            const int node0 = mt*16 + q*4;                                       \
            _Pragma("unroll")                                                    \
            for (int nt = 0; nt < 2; ++nt) {                                     \
                v4f acc = {0.f,0.f,0.f,0.f};                                     \
                acc = __builtin_amdgcn_mfma_f32_16x16x32_f16(                    \
                        af, nt ? w1f1 : w1f0, acc, 0,0,0);                       \
                const int colw = nt*16 + c;                                      \
                if (colw < 30 && node0 <= 68) {                                  \
                    const int e = colw / 10, s = colw - e*10;                    \
                    v4h hv = {(_Float16)acc[0],(_Float16)acc[1],                 \
                              (_Float16)acc[2],(_Float16)acc[3]};                \
                    *(v4h*)&sm.U[s*USTR + e*72 + node0] = hv;                    \
                }                                                                \
            }                                                                    \
        }                                                                        \
    } while(0)

    PHASE1();
    __syncthreads();

    #pragma unroll 1
    for (int step = 0; step < STEPS; ++step) {
        // ---- P2 (operand-swapped): a_in^T = U-frag (A) x adj-frag (B)
        //      D[row=s=q*4+r][col=node=mt*16+c] -> ONE packed v4h/v2h store.
        //      bfr reads for c>=10 land in own cat slice (finite; rows dropped).
        {
            v8h bfr[7];
            #pragma unroll
            for (int kt = 0; kt < 7; ++kt)
                bfr[kt] = *(const v8h*)&sm.U[c*USTR + q*8 + kt*32];
            #pragma unroll
            for (int mt = 0; mt < 5; ++mt) {
                v4f acc = {0.f,0.f,0.f,0.f};
                #pragma unroll
                for (int kt = 0; kt < 7; ++kt)
                    acc = __builtin_amdgcn_mfma_f32_16x16x32_f16(
                        bfr[kt], adj[mt*7+kt], acc, 0,0,0);
                const int node = mt*16 + c;
                if (node < NN) {
                    const v4h hv = {(_Float16)acc[0],(_Float16)acc[1],
                                    (_Float16)acc[2],(_Float16)acc[3]};
                    _Float16* wp = &sm.cat[node*CATN + q*4];   // s = q*4..q*4+3
                    if (q < 2)       *(v4h*)wp = hv;
                    else if (q == 2) *(v2h*)wp = (v2h){hv[0], hv[1]};   // s=8,9
                }
            }
        }
        __syncthreads();   // a_in visible

        // ---- P3 phase A: r,z + rp-write for ALL 5 node-tiles (5-way ILP),
        //      ONE fence. z + old prop carried in f16 regs (20 VGPRs).
        v4h zgp[5], pgp[5];
        {
            #pragma unroll
            for (int nt = 0; nt < 5; ++nt) {
                const int node = nt*16 + c;
                const v8h bf = *(const v8h*)&sm.cat[node*CATN + q*8];
                v4f ar = {0.f,0.f,0.f,0.f}, az = {0.f,0.f,0.f,0.f};
                ar = __builtin_amdgcn_mfma_f32_16x16x32_f16(wrf, bf, ar, 0,0,0);
                az = __builtin_amdgcn_mfma_f32_16x16x32_f16(wzf, bf, az, 0,0,0);
                const v4h pv = *(const v4h*)&sm.cat[node*CATN + 16 + q*4];
                v4h rp, zh;
                #pragma unroll
                for (int i = 0; i < 4; ++i) {
                    const float p = (float)pv[i];
                    zh[i] = (_Float16)fast_sigmoid(az[i]);
                    rp[i] = (_Float16)(fast_sigmoid(ar[i]) * p);
                }
                zgp[nt] = zh; pgp[nt] = pv;
                if (node < NN) {
                    _Float16* wp = &sm.cat[node*CATN + 16 + q*4];
                    if (q < 2)       *(v4h*)wp = rp;
                    else if (q == 2) *(v2h*)wp = (v2h){rp[0], rp[1]};
                }
            }
        }
        __syncthreads();   // rp visible cross-lane

        // ---- P3 phase B: h + state update for ALL 5 node-tiles
        {
            #pragma unroll
            for (int nt = 0; nt < 5; ++nt) {
                const int node = nt*16 + c;
                const v8h bf2 = *(const v8h*)&sm.cat[node*CATN + q*8];
                v4f ah = {0.f,0.f,0.f,0.f};
                ah = __builtin_amdgcn_mfma_f32_16x16x32_f16(whf, bf2, ah, 0,0,0);
                v4h pn;
                #pragma unroll
                for (int i = 0; i < 4; ++i) {
                    const float hh = fast_tanh(ah[i]);
                    const float p  = (float)pgp[nt][i];
                    const float z  = (float)zgp[nt][i];
                    pn[i] = (_Float16)(p + z*(hh - p));
                }
                if (node < NN) {
                    _Float16* wp = &sm.cat[node*CATN + 16 + q*4];
                    if (q < 2)       *(v4h*)wp = pn;
                    else if (q == 2) *(v2h*)wp = (v2h){pn[0], pn[1]};
                }
            }
        }
        __syncthreads();   // new prop visible

        // ---- P1 for next step
        if (step < STEPS-1) {
            PHASE1();
            __syncthreads();
        }
    }
    #undef PHASE1

    // ---- epilogue: one output per node
    for (int n2 = lane; n2 < NN; n2 += 64) {
        const _Float16* pc = &sm.cat[n2*CATN + 16];
        const v8h p8 = *(const v8h*)pc;
        const v2h p2 = *(const v2h*)(pc + 8);
        float pr[10];
        #pragma unroll
        for (int i = 0; i < 8; ++i) pr[i] = (float)p8[i];
        pr[8] = (float)p2[0]; pr[9] = (float)p2[1];
        const float av = (float)ann_g[gid*NN + n2];
        float o = gw[PBO2];
        #pragma unroll
        for (int s = 0; s < 10; ++s) {
            const float* wr_ = &gw[PWO1 + s*12];
            float acc = wr_[11] + wr_[10]*av;
            #pragma unroll
            for (int d = 0; d < 10; ++d) acc += pr[d]*wr_[d];
            o += fast_tanh(acc) * gw[PWO2 + s];
        }
        out_g[gid*NN + n2] = (T)o;
    }
}

// 4 waves/WG, each an independent graph on its own LDS slice. All barriers are
// uniform (identical code on all waves) -> lockstep coupling ~tens of cycles.
// min-waves=2 -> 256-VGPR cap (r1 lesson: higher min SPILLS). Expect ~120 VGPR
// -> 4 waves/SIMD tier; LDS 39104 B -> 4 WG/CU -> 16 waves/CU.
// Tripwires: VGPR > 128 (occupancy halves); WRITE_SIZE >> 4.9MB (spill).
__global__ __launch_bounds__(TPB, 2)
void ggnn_kernel(const void* annv, void* outv)
{
    __shared__ Smem sm[NWAVES];
    const int wave = threadIdx.x >> 6;
    const int lane = threadIdx.x & 63;
    const int gid  = blockIdx.x * NWAVES + wave;
    if (g_flag)
        run_impl<__hip_bfloat16>(annv, outv, sm[wave], lane, gid);
    else
        run_impl<float>(annv, outv, sm[wave], lane, gid);
}

extern "C" void kernel_launch(void* const* d_in, const int* in_sizes, int n_in,
                              void* d_out, int out_size, void* d_ws, size_t ws_size,
                              hipStream_t stream) {
    (void)in_sizes; (void)n_in; (void)out_size; (void)d_ws; (void)ws_size;
    hipLaunchKernelGGL(prep_kernel, dim3(PREPB), dim3(256), 0, stream,
        d_in[0], d_in[1], d_in[2], d_in[3], d_in[4], d_in[5], d_in[6],
        d_in[7], d_in[8], d_in[9], d_in[10], d_in[11], d_in[12], d_in[13]);
    hipLaunchKernelGGL(ggnn_kernel, dim3(NBLK), dim3(TPB), 0, stream,
        d_in[0], d_out);
}

// Round 8
// 285.462 us; speedup vs baseline: 1.0371x; 1.0371x over previous
//
#include <hip/hip_runtime.h>
#include <hip/hip_bf16.h>

typedef _Float16 v8h __attribute__((ext_vector_type(8)));
typedef _Float16 v4h __attribute__((ext_vector_type(4)));
typedef _Float16 v2h __attribute__((ext_vector_type(2)));
typedef float    v4f __attribute__((ext_vector_type(4)));

#define NTOT  16384
#define NN    70
#define STEPS 5
#define TPB   64                     // ONE wave per block
#define GPW   2                      // TWO independent graphs per wave (ILP)
#define NBLK  (NTOT/GPW)             // 8192 blocks
// r0-r7 invariant: ~7 wave-slots/CU active and 67-81 waves/us chip-wide in
// EVERY config; raising residency caps never helped (r4==r6 null, r7 worse).
// Only per-wave wall W ever moved perf (r4). W is ~70% latency stall at
// ~1.75 waves/SIMD -> fill it with a SECOND graph's instructions in the SAME
// wave: phases interleaved pairwise, adj/weight regs shared.
#define CATN  40                     // cat node stride (r6-validated; CATN 32
                                     // unswizzled doubles conflicts -- r7)
#define CATH  3208                   // 80 nodes * 40 + pad
#define USTR  232                    // U col stride (halves): 116 dw == 20 mod 32
#define UH    (10*USTR)              // 10 real cols; phantom-col B-frag reads
                                     // (c>=10) land in same graph's cat: finite,
                                     // D rows 10..15 discarded (r2/r3/r6-validated)

// epilogue weights (fp32, global scalar loads)
#define PWO1 0                       // 10 rows x 12: [Wo1[s][0..9], ann_coef, bo1[s]]
#define PWO2 120
#define PBO2 130
#define NWP  132

// fp16 fragment images (built by prep):
//  [0..1023]     P1 B-frags Wstack, 2 tiles:  nt*512 + lane*8 + j
//  [1024..2047]  P3 A-frags Wr | Wz:          mt*512 + lane*8 + j
//  [2048..2559]  P3 A-frag  Wh:               lane*8 + j
//  [2560..20479] adjacency frags:             2560 + (mt*7+kt)*512 + lane*8 + j
//  NOTE: A-frag image of M == B-frag image of M^T for 16x16x32 (identical
//  (lane,j)->(row/col,k) map), so adjacency images serve as swapped-P2's B operand.
#define OFR  1024
#define OFZ  1536
#define OFH  2048
#define OFA  2560
#define NWF  20480
#define PREPB 40

__device__ __align__(16) float    g_w[NWP];
__device__ __align__(16) _Float16 g_wf[NWF];
__device__ int g_flag;

__device__ __forceinline__ float fast_sigmoid(float x) {
    return __builtin_amdgcn_rcpf(1.0f + __expf(-x));
}
__device__ __forceinline__ float fast_tanh(float x) {
    float ax = fabsf(x);
    float e  = __expf(-2.0f * ax);
    float t  = (1.0f - e) * __builtin_amdgcn_rcpf(1.0f + e);
    return copysignf(t, x);
}

struct __align__(16) Smem {
    _Float16 U[UH];      // 4640 B: U[col=s][k=e*72+node]
    _Float16 cat[CATH];  // 6416 B: cat[node][k]; k0..9=a_in, 16..25=prop, 26=1
};
// 11056 B per graph; block = 2 graphs = 22112 B -> alloc ~22528 -> 7 blocks/CU
// (= the observed active wave-slot count) holding 14 graphs in flight vs r6's 7.

// ---- prep: probe dtype; build epilogue weights + all fp16 fragment images ----
__global__ void prep_kernel(const void* annv, const void* Av,
    const void* winv, const void* binv, const void* wrv, const void* brv,
    const void* wzv, const void* bzv, const void* whv, const void* bhv,
    const void* wo1v, const void* bo1v, const void* wo2v, const void* bo2v)
{
    __shared__ int sflag;
    if (threadIdx.x == 0) {
        const unsigned short* u = (const unsigned short*)annv;
        int good = 0;
        for (int k = 0; k < 128; ++k) {
            unsigned short bb = u[k];
            int ex = (bb >> 7) & 0xFF;
            if (bb == 0 || (ex >= 101 && ex <= 131)) ++good;
        }
        sflag = (good >= 112) ? 1 : 0;
        if (blockIdx.x == 0) g_flag = sflag;
    }
    __syncthreads();
    const int f = sflag;
    #define RD(p, i) (f ? (float)((const __hip_bfloat16*)(p))[i] : ((const float*)(p))[i])
    const int tid = threadIdx.x;
    if (blockIdx.x == 0) {
        for (int idx = tid; idx < 120; idx += blockDim.x) {
            const int s = idx / 12, cc = idx - s*12;
            g_w[PWO1 + idx] = (cc < 11) ? RD(wo1v, s*11 + cc) : RD(bo1v, s);
        }
        for (int idx = tid; idx < 10; idx += blockDim.x) g_w[PWO2 + idx] = RD(wo2v, idx);
        if (tid == 0) { g_w[PBO2] = RD(bo2v, 0); g_w[PBO2+1] = 0.f; }
    }
    for (int idx = blockIdx.x*blockDim.x + tid; idx < NWF; idx += gridDim.x*blockDim.x) {
        float val = 0.f;
        if (idx < OFR) {
            // P1 B-frag: B[k][col=(e,s)]; k 16..25 -> Win[e][s][k-16], k 26 -> b_in
            const int nt = idx >> 9, rem = idx & 511, lane = rem >> 3, j = rem & 7;
            const int k = ((lane >> 4) << 3) + j, col = nt*16 + (lane & 15);
            if (col < 30) {
                const int e = col / 10, s = col - e*10;
                if (k >= 16 && k < 26) val = RD(winv, e*100 + s*10 + (k-16));
                else if (k == 26)      val = RD(binv, e*10 + s);
            }
        } else if (idx < OFH) {
            // P3 A-frags Wr/Wz: A[row=s][k]; k<10 -> W[s][k], 16..25 -> W[s][10+..], 26 -> bias
            const int i2 = idx - OFR;
            const int mt = i2 >> 9, rem = i2 & 511, lane = rem >> 3, j = rem & 7;
            const int k = ((lane >> 4) << 3) + j, s = lane & 15;
            if (s < 10) {
                const void* Wv = mt ? wzv : wrv;
                const void* bv = mt ? bzv : brv;
                if (k < 10)                 val = RD(Wv, s*20 + k);
                else if (k >= 16 && k < 26) val = RD(Wv, s*20 + 10 + (k-16));
                else if (k == 26)           val = RD(bv, s);
            }
        } else if (idx < OFA) {
            const int i2 = idx - OFH;
            const int lane = i2 >> 3, j = i2 & 7;
            const int k = ((lane >> 4) << 3) + j, s = lane & 15;
            if (s < 10) {
                if (k < 10)                 val = RD(whv, s*20 + k);
                else if (k >= 16 && k < 26) val = RD(whv, s*20 + 10 + (k-16));
                else if (k == 26)           val = RD(bhv, s);
            }
        } else {
            // adjacency frag: A[m=node][k=e*72+mm]; zero at pads
            const int i2 = idx - OFA;
            const int w = i2 / 3584, rem = i2 - w*3584;
            const int kt = rem >> 9, r2 = rem & 511, lane = r2 >> 3, j = r2 & 7;
            const int m = w*16 + (lane & 15);
            const int k = kt*32 + ((lane >> 4) << 3) + j;
            const int e = k / 72, mm = k - e*72;
            if (m < NN && e < 3 && mm < NN) val = RD(Av, m*210 + e*70 + mm);
        }
        g_wf[idx] = (_Float16)val;
    }
    #undef RD
}

template<typename T>
__device__ __forceinline__ void run2(const void* annv, void* outv,
                                     Smem& s0, Smem& s1, const int g0, const int g1)
{
    const T* ann_g = (const T*)annv;
    T* out_g       = (T*)outv;
    const int lane = threadIdx.x;    // single wave
    const int q    = lane >> 4;
    const int c    = lane & 15;
    const float* __restrict__ gw = g_w;

    // ---- shared fragment preload (ONE set serves BOTH graphs; loop-hoisted
    //      array form = r4's winning schedule; no sched_barrier pinning)
    const v8h w1f0 = *(const v8h*)&g_wf[       lane*8];
    const v8h w1f1 = *(const v8h*)&g_wf[512  + lane*8];
    const v8h wrf  = *(const v8h*)&g_wf[OFR  + lane*8];
    const v8h wzf  = *(const v8h*)&g_wf[OFZ  + lane*8];
    const v8h whf  = *(const v8h*)&g_wf[OFH  + lane*8];
    v8h adj[35];
    #pragma unroll
    for (int i = 0; i < 35; ++i)
        adj[i] = *(const v8h*)&g_wf[OFA + i*512 + lane*8];

    // ---- zero both LDS slices (phantom rows/cols MUST be finite-zero)
    {
        const int4 zz = {0,0,0,0};
        int4* z0 = (int4*)&s0;
        int4* z1 = (int4*)&s1;
        #pragma unroll 4
        for (int i = lane; i < (int)(sizeof(Smem)/16); i += TPB) { z0[i] = zz; z1[i] = zz; }
    }
    __syncthreads();

    // ---- seed both graphs: prop[0]=ann at k=16, bias-one at k=26
    for (int n2 = lane; n2 < NN; n2 += TPB) {
        s0.cat[n2*CATN + 16] = (_Float16)(float)ann_g[g0*NN + n2];
        s1.cat[n2*CATN + 16] = (_Float16)(float)ann_g[g1*NN + n2];
        s0.cat[n2*CATN + 26] = (_Float16)1.0f;
        s1.cat[n2*CATN + 26] = (_Float16)1.0f;
    }
    __syncthreads();

    // ---- P1 (paired): ins(prop) -> U for both graphs, interleaved per mt
    #define PHASE1() do {                                                        \
        _Pragma("unroll")                                                        \
        for (int mt = 0; mt < 5; ++mt) {                                         \
            const v8h af0 = *(const v8h*)&s0.cat[(mt*16 + c)*CATN + q*8];        \
            const v8h af1 = *(const v8h*)&s1.cat[(mt*16 + c)*CATN + q*8];        \
            const int node0 = mt*16 + q*4;                                       \
            _Pragma("unroll")                                                    \
            for (int nt = 0; nt < 2; ++nt) {                                     \
                const v8h wb = nt ? w1f1 : w1f0;                                 \
                v4f a0 = {0.f,0.f,0.f,0.f}, a1 = {0.f,0.f,0.f,0.f};              \
                a0 = __builtin_amdgcn_mfma_f32_16x16x32_f16(af0, wb, a0, 0,0,0); \
                a1 = __builtin_amdgcn_mfma_f32_16x16x32_f16(af1, wb, a1, 0,0,0); \
                const int colw = nt*16 + c;                                      \
                if (colw < 30 && node0 <= 68) {                                  \
                    const int e = colw / 10, s = colw - e*10;                    \
                    *(v4h*)&s0.U[s*USTR + e*72 + node0] =                        \
                        (v4h){(_Float16)a0[0],(_Float16)a0[1],                   \
                              (_Float16)a0[2],(_Float16)a0[3]};                  \
                    *(v4h*)&s1.U[s*USTR + e*72 + node0] =                        \
                        (v4h){(_Float16)a1[0],(_Float16)a1[1],                   \
                              (_Float16)a1[2],(_Float16)a1[3]};                  \
                }                                                                \
            }                                                                    \
        }                                                                        \
    } while(0)

    PHASE1();
    __syncthreads();

    #pragma unroll 1
    for (int step = 0; step < STEPS; ++step) {
        // ---- P2 (paired, operand-swapped): each adj frag feeds BOTH graphs'
        //      MFMAs back-to-back (one reload serves two uses -- r2 lesson).
        {
            v8h bfr0[7], bfr1[7];
            #pragma unroll
            for (int kt = 0; kt < 7; ++kt) {
                bfr0[kt] = *(const v8h*)&s0.U[c*USTR + q*8 + kt*32];
                bfr1[kt] = *(const v8h*)&s1.U[c*USTR + q*8 + kt*32];
            }
            #pragma unroll
            for (int mt = 0; mt < 5; ++mt) {
                v4f a0 = {0.f,0.f,0.f,0.f}, a1 = {0.f,0.f,0.f,0.f};
                #pragma unroll
                for (int kt = 0; kt < 7; ++kt) {
                    const v8h av = adj[mt*7+kt];
                    a0 = __builtin_amdgcn_mfma_f32_16x16x32_f16(bfr0[kt], av, a0, 0,0,0);
                    a1 = __builtin_amdgcn_mfma_f32_16x16x32_f16(bfr1[kt], av, a1, 0,0,0);
                }
                const int node = mt*16 + c;
                if (node < NN) {
                    const v4h h0 = {(_Float16)a0[0],(_Float16)a0[1],
                                    (_Float16)a0[2],(_Float16)a0[3]};
                    const v4h h1 = {(_Float16)a1[0],(_Float16)a1[1],
                                    (_Float16)a1[2],(_Float16)a1[3]};
                    _Float16* w0 = &s0.cat[node*CATN + q*4];   // s = q*4..q*4+3
                    _Float16* w1 = &s1.cat[node*CATN + q*4];
                    if (q < 2)       { *(v4h*)w0 = h0; *(v4h*)w1 = h1; }
                    else if (q == 2) { *(v2h*)w0 = (v2h){h0[0], h0[1]};
                                       *(v2h*)w1 = (v2h){h1[0], h1[1]}; }
                }
            }
        }
        __syncthreads();   // a_in visible

        // ---- P3 phase A (paired): r,z + rp-write, all 5 node-tiles, ONE fence
        v4h zgp0[5], pgp0[5], zgp1[5], pgp1[5];
        {
            #pragma unroll
            for (int nt = 0; nt < 5; ++nt) {
                const int node = nt*16 + c;
                const v8h bf0 = *(const v8h*)&s0.cat[node*CATN + q*8];
                const v8h bf1 = *(const v8h*)&s1.cat[node*CATN + q*8];
                v4f ar0 = {0.f,0.f,0.f,0.f}, az0 = {0.f,0.f,0.f,0.f};
                v4f ar1 = {0.f,0.f,0.f,0.f}, az1 = {0.f,0.f,0.f,0.f};
                ar0 = __builtin_amdgcn_mfma_f32_16x16x32_f16(wrf, bf0, ar0, 0,0,0);
                ar1 = __builtin_amdgcn_mfma_f32_16x16x32_f16(wrf, bf1, ar1, 0,0,0);
                az0 = __builtin_amdgcn_mfma_f32_16x16x32_f16(wzf, bf0, az0, 0,0,0);
                az1 = __builtin_amdgcn_mfma_f32_16x16x32_f16(wzf, bf1, az1, 0,0,0);
                const v4h pv0 = *(const v4h*)&s0.cat[node*CATN + 16 + q*4];
                const v4h pv1 = *(const v4h*)&s1.cat[node*CATN + 16 + q*4];
                v4h rp0, zh0, rp1, zh1;
                #pragma unroll
                for (int i = 0; i < 4; ++i) {
                    const float p0 = (float)pv0[i], p1 = (float)pv1[i];
                    zh0[i] = (_Float16)fast_sigmoid(az0[i]);
                    zh1[i] = (_Float16)fast_sigmoid(az1[i]);
                    rp0[i] = (_Float16)(fast_sigmoid(ar0[i]) * p0);
                    rp1[i] = (_Float16)(fast_sigmoid(ar1[i]) * p1);
                }
                zgp0[nt] = zh0; pgp0[nt] = pv0;
                zgp1[nt] = zh1; pgp1[nt] = pv1;
                if (node < NN) {
                    _Float16* w0 = &s0.cat[node*CATN + 16 + q*4];
                    _Float16* w1 = &s1.cat[node*CATN + 16 + q*4];
                    if (q < 2)       { *(v4h*)w0 = rp0; *(v4h*)w1 = rp1; }
                    else if (q == 2) { *(v2h*)w0 = (v2h){rp0[0], rp0[1]};
                                       *(v2h*)w1 = (v2h){rp1[0], rp1[1]}; }
                }
            }
        }
        __syncthreads();   // rp visible cross-lane

        // ---- P3 phase B (paired): h + state update, all 5 node-tiles
        {
            #pragma unroll
            for (int nt = 0; nt < 5; ++nt) {
                const int node = nt*16 + c;
                const v8h bf0 = *(const v8h*)&s0.cat[node*CATN + q*8];
                const v8h bf1 = *(const v8h*)&s1.cat[node*CATN + q*8];
                v4f ah0 = {0.f,0.f,0.f,0.f}, ah1 = {0.f,0.f,0.f,0.f};
                ah0 = __builtin_amdgcn_mfma_f32_16x16x32_f16(whf, bf0, ah0, 0,0,0);
                ah1 = __builtin_amdgcn_mfma_f32_16x16x32_f16(whf, bf1, ah1, 0,0,0);
                v4h pn0, pn1;
                #pragma unroll
                for (int i = 0; i < 4; ++i) {
                    const float h0 = fast_tanh(ah0[i]);
                    const float h1 = fast_tanh(ah1[i]);
                    const float p0 = (float)pgp0[nt][i], z0 = (float)zgp0[nt][i];
                    const float p1 = (float)pgp1[nt][i], z1 = (float)zgp1[nt][i];
                    pn0[i] = (_Float16)(p0 + z0*(h0 - p0));
                    pn1[i] = (_Float16)(p1 + z1*(h1 - p1));
                }
                if (node < NN) {
                    _Float16* w0 = &s0.cat[node*CATN + 16 + q*4];
                    _Float16* w1 = &s1.cat[node*CATN + 16 + q*4];
                    if (q < 2)       { *(v4h*)w0 = pn0; *(v4h*)w1 = pn1; }
                    else if (q == 2) { *(v2h*)w0 = (v2h){pn0[0], pn0[1]};
                                       *(v2h*)w1 = (v2h){pn1[0], pn1[1]}; }
                }
            }
        }
        __syncthreads();   // new prop visible

        // ---- P1 for next step
        if (step < STEPS-1) {
            PHASE1();
            __syncthreads();
        }
    }
    #undef PHASE1

    // ---- epilogue: one output per node, both graphs
    for (int n2 = lane; n2 < NN; n2 += TPB) {
        const float av0 = (float)ann_g[g0*NN + n2];
        const float av1 = (float)ann_g[g1*NN + n2];
        float pr0[10], pr1[10];
        {
            const v8h p8 = *(const v8h*)&s0.cat[n2*CATN + 16];
            const v2h p2 = *(const v2h*)&s0.cat[n2*CATN + 24];
            #pragma unroll
            for (int i = 0; i < 8; ++i) pr0[i] = (float)p8[i];
            pr0[8] = (float)p2[0]; pr0[9] = (float)p2[1];
        }
        {
            const v8h p8 = *(const v8h*)&s1.cat[n2*CATN + 16];
            const v2h p2 = *(const v2h*)&s1.cat[n2*CATN + 24];
            #pragma unroll
            for (int i = 0; i < 8; ++i) pr1[i] = (float)p8[i];
            pr1[8] = (float)p2[0]; pr1[9] = (float)p2[1];
        }
        float o0 = gw[PBO2], o1 = gw[PBO2];
        #pragma unroll
        for (int s = 0; s < 10; ++s) {
            const float* wr_ = &gw[PWO1 + s*12];
            float a0 = wr_[11] + wr_[10]*av0;
            float a1 = wr_[11] + wr_[10]*av1;
            #pragma unroll
            for (int d = 0; d < 10; ++d) { a0 += pr0[d]*wr_[d]; a1 += pr1[d]*wr_[d]; }
            o0 += fast_tanh(a0) * gw[PWO2 + s];
            o1 += fast_tanh(a1) * gw[PWO2 + s];
        }
        out_g[g0*NN + n2] = (T)o0;
        out_g[g1*NN + n2] = (T)o1;
    }
}

// min-waves=2 -> 256-VGPR cap (r1 lesson: higher min SPILLS). Expected VGPR
// ~170-230: shared adj/weights + duplicated transients. Tripwire:
// WRITE_SIZE >> 4.9 MB => spill => revert to single-graph r6 kernel.
__global__ __launch_bounds__(TPB, 2)
void ggnn_kernel(const void* annv, void* outv)
{
    __shared__ Smem sm0, sm1;
    const int g0 = blockIdx.x * GPW;
    if (g_flag)
        run2<__hip_bfloat16>(annv, outv, sm0, sm1, g0, g0+1);
    else
        run2<float>(annv, outv, sm0, sm1, g0, g0+1);
}

extern "C" void kernel_launch(void* const* d_in, const int* in_sizes, int n_in,
                              void* d_out, int out_size, void* d_ws, size_t ws_size,
                              hipStream_t stream) {
    (void)in_sizes; (void)n_in; (void)out_size; (void)d_ws; (void)ws_size;
    hipLaunchKernelGGL(prep_kernel, dim3(PREPB), dim3(256), 0, stream,
        d_in[0], d_in[1], d_in[2], d_in[3], d_in[4], d_in[5], d_in[6],
        d_in[7], d_in[8], d_in[9], d_in[10], d_in[11], d_in[12], d_in[13]);
    hipLaunchKernelGGL(ggnn_kernel, dim3(NBLK), dim3(TPB), 0, stream,
        d_in[0], d_out);
}